// Round 9
// baseline (177.431 us; speedup 1.0000x reference)
//
#include <hip/hip_runtime.h>
#include <hip/hip_fp16.h>

#define NF 14
#define DIMOUT 16
#define BSH 9        // 512 nodes per bucket
#define NPBKT 512
#define NBKT 256     // bucket count (used: ceil(N/512) = 196)
#define C1 4096      // edges per block in bucket passes
#define GSUB 8       // subchunks per bucket in node-level passes

// int64 edge buffer <=> odd 32-bit words (high halves) all zero (ids < 2^31)
__device__ __forceinline__ bool detect64(const int* e32) {
    bool is64 = true;
#pragma unroll
    for (int i = 1; i < 64; i += 2) is64 &= (e32[i] == 0);
    return is64;
}

// ---- per-block bucket histogram (transposed write) ----
__global__ __launch_bounds__(256) void k_lhist(const void* __restrict__ edges,
                                               int* __restrict__ lhistT, int E, int NBLK) {
    __shared__ int h[NBKT];
    const int t = threadIdx.x;
    h[t] = 0;
    __syncthreads();
    const int* e32 = (const int*)edges;
    const long long* e64 = (const long long*)edges;
    const bool is64 = detect64(e32);
    const int base = blockIdx.x * C1;
    const int cnt = min(C1, E - base);
    for (int j = t; j < cnt; j += 256) {
        int i = base + j;
        int dst = is64 ? (int)__builtin_nontemporal_load(e64 + (size_t)E + i)
                       : __builtin_nontemporal_load(e32 + (size_t)E + i);
        atomicAdd(&h[dst >> BSH], 1);
    }
    __syncthreads();
    lhistT[(size_t)t * NBLK + blockIdx.x] = h[t];
}

// ---- per-bucket scan over blocks ----
__global__ __launch_bounds__(256) void k_cscan(const int* __restrict__ lhistT,
                                               int* __restrict__ lbase,
                                               int* __restrict__ btot, int NBLK) {
    const int b = blockIdx.x;
    const int t = threadIdx.x;
    const int IPT = (NBLK + 255) / 256;
    int v[8];
    int s = 0;
    for (int k = 0; k < IPT; ++k) {
        int j = t * IPT + k;
        int x = (j < NBLK) ? lhistT[(size_t)b * NBLK + j] : 0;
        v[k] = x;
        s += x;
    }
    __shared__ int sm[256];
    sm[t] = s;
    __syncthreads();
    for (int d = 1; d < 256; d <<= 1) {
        int u = (t >= d) ? sm[t - d] : 0;
        __syncthreads();
        sm[t] += u;
        __syncthreads();
    }
    int run = sm[t] - s;
    for (int k = 0; k < IPT; ++k) {
        int j = t * IPT + k;
        if (j < NBLK) {
            lbase[(size_t)b * NBLK + j] = run;
            run += v[k];
        }
    }
    if (t == 255) btot[b] = sm[255];
}

// ---- scan bucket totals -> regions ----
__global__ __launch_bounds__(NBKT) void k_gscan(const int* __restrict__ btot,
                                                int* __restrict__ gregion) {
    __shared__ int sm[NBKT];
    int t = threadIdx.x;
    int v = btot[t];
    sm[t] = v;
    __syncthreads();
    for (int d = 1; d < NBKT; d <<= 1) {
        int u = (t >= d) ? sm[t - d] : 0;
        __syncthreads();
        sm[t] += u;
        __syncthreads();
    }
    gregion[t] = sm[t] - v;
    if (t == NBKT - 1) gregion[NBKT] = sm[t];
}

// ---- bucket scatter: block-local LDS counting sort, runs at exact bases ----
// packed entry: (dst & 511) << 17 | src
__global__ __launch_bounds__(256) void k_scatter(const void* __restrict__ edges,
                                                 const int* __restrict__ gregion,
                                                 const int* __restrict__ lbase,
                                                 unsigned int* __restrict__ pairs,
                                                 int E, int NBLK) {
    __shared__ unsigned int raw[C1];
    __shared__ unsigned int srt[C1];
    __shared__ unsigned short bkt[C1];
    __shared__ unsigned char sbk[C1];
    __shared__ int hist[NBKT], scn[NBKT], gb[NBKT], cur[NBKT];
    const int* e32 = (const int*)edges;
    const long long* e64 = (const long long*)edges;
    const bool is64 = detect64(e32);
    const int t = threadIdx.x;
    const int base = blockIdx.x * C1;
    const int cnt = min(C1, E - base);
    hist[t] = 0;
    cur[t] = 0;
    __syncthreads();
    for (int j = t; j < cnt; j += 256) {
        int i = base + j;
        int src, dst;
        if (is64) {
            src = (int)__builtin_nontemporal_load(e64 + i);
            dst = (int)__builtin_nontemporal_load(e64 + (size_t)E + i);
        } else {
            src = __builtin_nontemporal_load(e32 + i);
            dst = __builtin_nontemporal_load(e32 + (size_t)E + i);
        }
        int b = dst >> BSH;
        raw[j] = (unsigned int)src | ((unsigned int)(dst & (NPBKT - 1)) << 17);
        bkt[j] = (unsigned short)b;
        atomicAdd(&hist[b], 1);
    }
    __syncthreads();
    int v = hist[t];
    scn[t] = v;
    __syncthreads();
    for (int d = 1; d < NBKT; d <<= 1) {
        int u = (t >= d) ? scn[t - d] : 0;
        __syncthreads();
        scn[t] += u;
        __syncthreads();
    }
    int ex = scn[t] - v;
    gb[t] = gregion[t] + lbase[(size_t)t * NBLK + blockIdx.x];
    __syncthreads();
    scn[t] = ex;
    __syncthreads();
    for (int j = t; j < cnt; j += 256) {
        int b = bkt[j];
        int r = atomicAdd(&cur[b], 1);
        int pos = scn[b] + r;
        srt[pos] = raw[j];
        sbk[pos] = (unsigned char)b;
    }
    __syncthreads();
    for (int j = t; j < cnt; j += 256) {
        int b = sbk[j];
        pairs[gb[b] + (j - scn[b])] = srt[j];
    }
}

// ---- node-level histogram per (bucket, subchunk); g-major layout ----
__global__ __launch_bounds__(256) void k_nhist(const unsigned int* __restrict__ pairs,
                                               const int* __restrict__ gregion,
                                               int* __restrict__ nh, int N) {
    const int b = blockIdx.x >> 3;
    const int g = blockIdx.x & 7;
    const int e0 = gregion[b], e1 = gregion[b + 1];
    const int L = e1 - e0;
    const int sb = e0 + ((L * g) >> 3);
    const int se = e0 + ((L * (g + 1)) >> 3);
    __shared__ int h[NPBKT];
    const int t = threadIdx.x;
    h[t] = 0;
    h[t + 256] = 0;
    __syncthreads();
    for (int e = sb + t; e < se; e += 256) atomicAdd(&h[pairs[e] >> 17], 1);
    __syncthreads();
    const int nbase = b << BSH;
    for (int l = t; l < NPBKT; l += 256) {
        int n = nbase + l;
        if (n < N) nh[(size_t)g * N + n] = h[l];
    }
}

// ---- per-node scan over subchunks + block scan of padded degrees
//      + FUSED prep: u0[n] = fp16(dinv * (x[n] @ W^T)), sentinel-row zeroing ----
__global__ __launch_bounds__(256) void k_nscan(int* __restrict__ nh,
                                               float* __restrict__ dinv,
                                               int2* __restrict__ lc,
                                               int* __restrict__ btot2,
                                               const float* __restrict__ x,
                                               const float* __restrict__ Wg,
                                               __half2* __restrict__ u0,
                                               __half2* __restrict__ u1, int N) {
    __shared__ float Wl[DIMOUT * NF];
    __shared__ int sm[256];
    const int t = threadIdx.x;
    if (t < DIMOUT * NF) Wl[t] = Wg[t];
    if (blockIdx.x == 0 && t < 8) {  // zero sentinel rows (src == N)
        u0[(size_t)N * 8 + t] = __floats2half2_rn(0.f, 0.f);
        u1[(size_t)N * 8 + t] = __floats2half2_rn(0.f, 0.f);
    }
    const int n = blockIdx.x * 256 + t;
    int c = 0, p = 0;
    float dn = 0.f;
    if (n < N) {
        int v[GSUB];
        int ex = 0;
#pragma unroll
        for (int g = 0; g < GSUB; ++g) v[g] = nh[(size_t)g * N + n];
#pragma unroll
        for (int g = 0; g < GSUB; ++g) {
            int vv = v[g];
            nh[(size_t)g * N + n] = ex;  // counts -> exclusive bases (in place)
            ex += vv;
        }
        c = ex;
        p = (c + 16) & ~15;  // self-loop + pad to multiple of 16
        dn = rsqrtf((float)(c + 1));
        dinv[n] = dn;
    }
    sm[t] = p;
    __syncthreads();
    for (int d = 1; d < 256; d <<= 1) {
        int u = (t >= d) ? sm[t - d] : 0;
        __syncthreads();
        sm[t] += u;
        __syncthreads();
    }
    if (n < N) {
        lc[n] = make_int2(sm[t] - p, c);  // (local offset, degree)
        float xr[NF];
#pragma unroll
        for (int f = 0; f < NF; ++f) xr[f] = x[(size_t)n * NF + f];
#pragma unroll
        for (int q = 0; q < 8; ++q) {
            float r0 = 0.f, r1 = 0.f;
#pragma unroll
            for (int f = 0; f < NF; ++f) {
                r0 += xr[f] * Wl[(2 * q) * NF + f];
                r1 += xr[f] * Wl[(2 * q + 1) * NF + f];
            }
            u0[(size_t)n * 8 + q] = __floats2half2_rn(dn * r0, dn * r1);
        }
    }
    if (t == 255) btot2[blockIdx.x] = sm[255];
}

// ---- scan per-block padded totals ----
__global__ __launch_bounds__(512) void k_gscan2(const int* __restrict__ btot2,
                                                int* __restrict__ bbase2, int nb) {
    __shared__ int sm[512];
    int t = threadIdx.x;
    int v = (t < nb) ? btot2[t] : 0;
    sm[t] = v;
    __syncthreads();
    for (int d = 1; d < 512; d <<= 1) {
        int u = (t >= d) ? sm[t - d] : 0;
        __syncthreads();
        sm[t] += u;
        __syncthreads();
    }
    if (t < nb) bbase2[t] = sm[t] - v;
}

// ---- finalize offsets, self-loop entries, sentinel pads ----
__global__ __launch_bounds__(256) void k_nfill(const int2* __restrict__ lc,
                                               const int* __restrict__ bbase2,
                                               int2* __restrict__ off2,
                                               int* __restrict__ srcs, int N) {
    const int n = blockIdx.x * 256 + threadIdx.x;
    if (n >= N) return;
    int2 l = lc[n];
    const int off = bbase2[blockIdx.x] + l.x;
    const int c = l.y;
    const int p = (c + 16) & ~15;
    off2[n] = make_int2(off, off + p);
    srcs[off] = n;  // self loop at slot 0
    for (int k = c + 1; k < p; ++k) srcs[off + k] = N;  // sentinel pad
}

// ---- node-level scatter per (bucket, subchunk) at precomputed bases ----
__global__ __launch_bounds__(256) void k_nscatter(const unsigned int* __restrict__ pairs,
                                                  const int* __restrict__ gregion,
                                                  const int* __restrict__ nh,
                                                  const int2* __restrict__ off2,
                                                  int* __restrict__ srcs, int N) {
    const int b = blockIdx.x >> 3;
    const int g = blockIdx.x & 7;
    const int e0 = gregion[b], e1 = gregion[b + 1];
    const int L = e1 - e0;
    const int sb = e0 + ((L * g) >> 3);
    const int se = e0 + ((L * (g + 1)) >> 3);
    __shared__ int cur[NPBKT];
    const int t = threadIdx.x;
    const int nbase = b << BSH;
    for (int l = t; l < NPBKT; l += 256) {
        int n = nbase + l;
        if (n < N) cur[l] = off2[n].x + 1 + nh[(size_t)g * N + n];
    }
    __syncthreads();
    for (int e = sb + t; e < se; e += 256) {
        unsigned int pr = pairs[e];
        int l = pr >> 17;
        int r = atomicAdd(&cur[l], 1);  // LDS only
        srcs[r] = (int)(pr & 0x1FFFFu);
    }
}

// ---- hop: wave per node, 16-way edge-parallel, 8B lanes, padded lists.
// Straight-line specializations for nch = 1/2/3 (covers ~99.6% of nodes):
// all srcs loads issue together, then all gathers -> 2 dependent-latency layers.
template <int FINAL>
__global__ __launch_bounds__(256) void k_hop(const uint2* __restrict__ u8,
                                             const int* __restrict__ srcs,
                                             const int2* __restrict__ off2,
                                             const float* __restrict__ dinv,
                                             const float* __restrict__ bias,
                                             uint2* __restrict__ outh,
                                             float* __restrict__ outf, int N) {
    const int lane = threadIdx.x & 63;
    const int fp = lane & 3;
    const int ep = lane >> 2;
    const int n = blockIdx.x * 4 + (threadIdx.x >> 6);
    if (n >= N) return;  // wave-uniform
    const int2 oo = off2[n];
    const int e = oo.x + ep;
    const int nch = (oo.y - oo.x) >> 4;
    float ax = 0.f, ay = 0.f, az = 0.f, aw = 0.f;
    auto acc32 = [&](uint2 q) {
        float2 a = __half22float2(*(__half2*)&q.x);
        float2 b = __half22float2(*(__half2*)&q.y);
        ax += a.x;
        ay += a.y;
        az += b.x;
        aw += b.y;
    };
    if (nch == 2) {
        int s0 = __builtin_nontemporal_load(srcs + e);
        int s1 = __builtin_nontemporal_load(srcs + e + 16);
        uint2 q0 = u8[(size_t)s0 * 4 + fp];
        uint2 q1 = u8[(size_t)s1 * 4 + fp];
        acc32(q0);
        acc32(q1);
    } else if (nch == 3) {
        int s0 = __builtin_nontemporal_load(srcs + e);
        int s1 = __builtin_nontemporal_load(srcs + e + 16);
        int s2 = __builtin_nontemporal_load(srcs + e + 32);
        uint2 q0 = u8[(size_t)s0 * 4 + fp];
        uint2 q1 = u8[(size_t)s1 * 4 + fp];
        uint2 q2 = u8[(size_t)s2 * 4 + fp];
        acc32(q0);
        acc32(q1);
        acc32(q2);
    } else if (nch == 1) {
        int s0 = __builtin_nontemporal_load(srcs + e);
        uint2 q0 = u8[(size_t)s0 * 4 + fp];
        acc32(q0);
    } else {  // rare high-degree tail
        int ee = e;
        const int end = oo.y;
        for (; ee + 16 < end; ee += 32) {
            int s0 = __builtin_nontemporal_load(srcs + ee);
            int s1 = __builtin_nontemporal_load(srcs + ee + 16);
            uint2 q0 = u8[(size_t)s0 * 4 + fp];
            uint2 q1 = u8[(size_t)s1 * 4 + fp];
            acc32(q0);
            acc32(q1);
        }
        if (ee < end) {
            int s0 = __builtin_nontemporal_load(srcs + ee);
            uint2 q0 = u8[(size_t)s0 * 4 + fp];
            acc32(q0);
        }
    }
#pragma unroll
    for (int d = 4; d <= 32; d <<= 1) {
        ax += __shfl_xor(ax, d);
        ay += __shfl_xor(ay, d);
        az += __shfl_xor(az, d);
        aw += __shfl_xor(aw, d);
    }
    if (ep != 0) return;
    float dn = dinv[n];
    if (!FINAL) {
        float s = dn * dn;
        __half2 h0 = __floats2half2_rn(s * ax, s * ay);
        __half2 h1 = __floats2half2_rn(s * az, s * aw);
        uint2 q;
        q.x = *(unsigned*)&h0;
        q.y = *(unsigned*)&h1;
        outh[(size_t)n * 4 + fp] = q;
    } else {
        float4 o;
        o.x = dn * ax + bias[4 * fp];
        o.y = dn * ay + bias[4 * fp + 1];
        o.z = dn * az + bias[4 * fp + 2];
        o.w = dn * aw + bias[4 * fp + 3];
        *(float4*)(outf + (size_t)n * DIMOUT + 4 * fp) = o;
    }
}

extern "C" void kernel_launch(void* const* d_in, const int* in_sizes, int n_in,
                              void* d_out, int out_size, void* d_ws, size_t ws_size,
                              hipStream_t stream) {
    const float* x = (const float*)d_in[0];
    const void* edges = d_in[1];
    const float* W = (const float*)d_in[2];
    const float* b = (const float*)d_in[3];
    float* out = (float*)d_out;

    const int N = in_sizes[0] / NF;  // 100000
    const int E = in_sizes[1] / 2;   // 3200000
    const int NBLK = (E + C1 - 1) / C1;
    const int NUSED = (N + NPBKT - 1) >> BSH;
    const int NBLK2 = (N + 255) / 256;

    char* ws = (char*)d_ws;
    size_t o = 0;
    auto alloc = [&](size_t bytes) -> void* {
        o = (o + 255) & ~(size_t)255;
        void* p = ws + o;
        o += bytes;
        return p;
    };
    int* lhistT = (int*)alloc((size_t)NBKT * NBLK * sizeof(int));
    int* lbase = (int*)alloc((size_t)NBKT * NBLK * sizeof(int));
    int* btot = (int*)alloc((size_t)NBKT * sizeof(int));
    int* gregion = (int*)alloc(((size_t)NBKT + 1) * sizeof(int));
    unsigned int* pairs = (unsigned int*)alloc((size_t)E * sizeof(unsigned int));
    int* srcs = (int*)alloc(((size_t)E + (size_t)16 * N + 256) * sizeof(int));
    int* nh = (int*)alloc((size_t)GSUB * N * sizeof(int));
    int2* lc = (int2*)alloc((size_t)N * sizeof(int2));
    int* btot2 = (int*)alloc((size_t)NBLK2 * sizeof(int));
    int* bbase2 = (int*)alloc((size_t)NBLK2 * sizeof(int));
    int2* off2 = (int2*)alloc((size_t)N * sizeof(int2));
    float* dinv = (float*)alloc((size_t)N * sizeof(float));
    __half* u0 = (__half*)alloc((size_t)(N + 1) * 16 * sizeof(__half));
    __half* u1 = (__half*)alloc((size_t)(N + 1) * 16 * sizeof(__half));
    (void)ws_size;
    (void)n_in;
    (void)out_size;

    k_lhist<<<NBLK, 256, 0, stream>>>(edges, lhistT, E, NBLK);
    k_cscan<<<NBKT, 256, 0, stream>>>(lhistT, lbase, btot, NBLK);
    k_gscan<<<1, NBKT, 0, stream>>>(btot, gregion);
    k_scatter<<<NBLK, 256, 0, stream>>>(edges, gregion, lbase, pairs, E, NBLK);
    k_nhist<<<NUSED * GSUB, 256, 0, stream>>>(pairs, gregion, nh, N);
    k_nscan<<<NBLK2, 256, 0, stream>>>(nh, dinv, lc, btot2, x, W, (__half2*)u0,
                                       (__half2*)u1, N);
    k_gscan2<<<1, 512, 0, stream>>>(btot2, bbase2, NBLK2);
    k_nfill<<<NBLK2, 256, 0, stream>>>(lc, bbase2, off2, srcs, N);
    k_nscatter<<<NUSED * GSUB, 256, 0, stream>>>(pairs, gregion, nh, off2, srcs, N);

    int hopgrid = (N + 3) / 4;
    k_hop<0><<<hopgrid, 256, 0, stream>>>((const uint2*)u0, srcs, off2, dinv, nullptr,
                                          (uint2*)u1, nullptr, N);
    k_hop<1><<<hopgrid, 256, 0, stream>>>((const uint2*)u1, srcs, off2, dinv, b,
                                          nullptr, out, N);
}